// Round 11
// baseline (1482.462 us; speedup 1.0000x reference)
//
#include <hip/hip_runtime.h>
#include <math.h>

#define B_ 16
#define N_ 4096
#define D_ 64
#define M_ 1024
#define K_ 32
#define RTOT (B_*M_*K_)          // 524288 rows
#define EPSF 1e-5f

// ---------------- ws layout (float units)
#define WT0B_OFF  0              // bf16 W0 perm [64 out][96 k] = 3072 f
#define WT1B_OFF  3072           // bf16 [64][64] = 2048 f
#define WT2B_OFF  5120           // bf16 [128][64] = 4096 f
#define ST_OFF    9216           // fallback stats s/q = 512
#define BN_OFF    9728           // ab0[128] ab1[128] ab2[256] = 512 (fallback)
#define NXW_OFF   10240          // new_xyz f32 [16384*3]
#define KIDX_OFF  59392          // knn idx int [524288] (fallback only)
#define PK_OFF    583680         // packed bf16 (max,min) [16384*128] uint32
#define Y0B_OFF   2680832        // bf16 Y0 raw [524288*64] = 16777216 f
#define PBF_OFF   19458048       // bf16 points [16*4096*64] = 2097152 f
#define PTS4_OFF  21555200       // float4 (x,y,z,pp) [65536] = 262144 f — OWN region (round-10 aliased Y0 -> race)
#define SB0_OFF   36235264       // [64][64]s + [64][64]q = 8192
#define SB1_OFF   (SB0_OFF + 8192)
#define SB2_OFF   (SB1_OFF + 8192)   // [64][128]s + [64][128]q = 16384
#define WS_FAST_BYTES ((unsigned long long)(SB2_OFF + 16384) * 4ull)

typedef __attribute__((ext_vector_type(8))) short bf16x8;
typedef __attribute__((ext_vector_type(4))) float f32x4;

__device__ inline unsigned bf16u(float x) {
    unsigned u = __float_as_uint(x);
    return (u + 0x7FFFu + ((u >> 16) & 1u)) >> 16;   // RN-even
}
__device__ inline float ubf(unsigned short h) {
    return __uint_as_float(((unsigned)h) << 16);
}

// u64 min across 16-lane row level via DPP (VALU pipe, no LDS)
#define ROR_MIN(kvar, CTRL) do {                                                   \
    unsigned _lo = (unsigned)(kvar), _hi = (unsigned)((kvar) >> 32);               \
    unsigned _rl = (unsigned)__builtin_amdgcn_update_dpp((int)_lo, (int)_lo, CTRL, 0xF, 0xF, false); \
    unsigned _rh = (unsigned)__builtin_amdgcn_update_dpp((int)_hi, (int)_hi, CTRL, 0xF, 0xF, false); \
    unsigned long long _o = ((unsigned long long)_rh << 32) | _rl;                 \
    if (_o < (kvar)) (kvar) = _o;                                                  \
} while (0)

// ============ fps + prep fused, 512 threads (8 waves, 8 pts/lane):
// blocks 0-15 FPS; 16 weights; 17-32 sb zero; 33..1056 points->bf16 (fast).
__global__ __launch_bounds__(512) void fps_kernel(const float* __restrict__ xyz,
                                                  float* __restrict__ out_newxyz,
                                                  float* __restrict__ out_fpsidx,
                                                  float* __restrict__ ws_newxyz,
                                                  float4* __restrict__ pts4g,
                                                  const float* __restrict__ W0,
                                                  const float* __restrict__ W1,
                                                  const float* __restrict__ W2,
                                                  const float* __restrict__ points,
                                                  float* __restrict__ ws, int fast) {
#pragma clang fp contract(off)
    __shared__ float4 pts[N_];
    __shared__ int selidx[M_];
    __shared__ __align__(32) unsigned long long red[2][8];
    const int bx = blockIdx.x;
    const int tid = threadIdx.x;
    if (bx >= 33) {               // points -> bf16, coalesced (512 thr x 8 f)
        unsigned short* pbf = (unsigned short*)(ws + PBF_OFF);
        size_t base = (size_t)(bx - 33) * 4096 + (size_t)tid * 8;
        const float4* s = (const float4*)(points + base);
        float4 f0 = s[0], f1 = s[1];
        uint4 u;
        u.x = bf16u(f0.x) | (bf16u(f0.y) << 16);
        u.y = bf16u(f0.z) | (bf16u(f0.w) << 16);
        u.z = bf16u(f1.x) | (bf16u(f1.y) << 16);
        u.w = bf16u(f1.z) | (bf16u(f1.w) << 16);
        *(uint4*)(pbf + base) = u;
        return;
    }
    if (bx >= 17) {               // zero stat buckets
        if (fast) {
            float* sb = ws + SB0_OFF + (bx - 17) * 2048;
            for (int i = tid; i < 2048; i += 512) sb[i] = 0.f;
        }
        return;
    }
    if (bx == 16) {               // weights + fallback-stats zero
        unsigned short* wt0b = (unsigned short*)(ws + WT0B_OFF);
        unsigned short* wt1b = (unsigned short*)(ws + WT1B_OFF);
        unsigned short* wt2b = (unsigned short*)(ws + WT2B_OFF);
        float* st = ws + ST_OFF;
        for (int i = tid; i < 512; i += 512) st[i] = 0.f;
        for (int i = tid; i < 64*96; i += 512) {
            int o = i / 96, k = i - o*96;
            float w = 0.f;
            if (k < 64)      w = W0[o*67 + 3 + k];
            else if (k < 67) w = W0[o*67 + (k - 64)];
            wt0b[i] = (unsigned short)bf16u(w);
        }
        for (int i = tid; i < 64*64; i += 512)  wt1b[i] = (unsigned short)bf16u(W1[i]);
        for (int i = tid; i < 128*64; i += 512) wt2b[i] = (unsigned short)bf16u(W2[i]);
        return;
    }
    // ---- FPS core: 8 waves, lane owns 8 contiguous points [tid*8, tid*8+8) --
    const int b = bx;
    const int lane = tid & 63, wave = tid >> 6;
    const float* xb = xyz + (size_t)b * N_ * 3;
    for (int i = tid; i < N_; i += 512) {
        float x = xb[i*3+0], y = xb[i*3+1], z = xb[i*3+2];
        pts[i] = make_float4(x, y, z, 0.f);
        if (pts4g) {
            float pp = x*x + y*y; pp = pp + z*z;   // matches knn's exact op order
            pts4g[b*N_ + i] = make_float4(x, y, z, pp);
        }
    }
    __syncthreads();
    float px[8], py[8], pz[8], dist[8];
#pragma unroll
    for (int j = 0; j < 8; ++j) {
        float4 p = pts[(tid << 3) + j];
        px[j] = p.x; py[j] = p.y; pz[j] = p.z;
        dist[j] = 3.4e38f;
    }
    int cur = N_/2;
    for (int t = 0; t < M_; ++t) {
        if (tid == (t & 511)) selidx[t] = cur;
        if (t == M_-1) break;
        float4 c4 = pts[cur];
        float cx = c4.x, cy = c4.y, cz = c4.z;
        // 4 contiguous-pair chains: {0,1},{2,3},{4,5},{6,7}; ascending combine
        float bm0 = -1.f, bm1 = -1.f, bm2 = -1.f, bm3 = -1.f;
        int bj0 = 0, bj1 = 2, bj2 = 4, bj3 = 6;
#pragma unroll
        for (int j = 0; j < 2; ++j) {
            {
                int k = j;
                float dx = px[k]-cx, dy = py[k]-cy, dz = pz[k]-cz;
                float a = dx*dx, b2 = dy*dy, c2 = dz*dz;
                float d = (a + b2) + c2;
                float nd = fminf(dist[k], d); dist[k] = nd;
                bool bt = nd > bm0; bm0 = bt ? nd : bm0; bj0 = bt ? k : bj0;
            }
            {
                int k = j + 2;
                float dx = px[k]-cx, dy = py[k]-cy, dz = pz[k]-cz;
                float a = dx*dx, b2 = dy*dy, c2 = dz*dz;
                float d = (a + b2) + c2;
                float nd = fminf(dist[k], d); dist[k] = nd;
                bool bt = nd > bm1; bm1 = bt ? nd : bm1; bj1 = bt ? k : bj1;
            }
            {
                int k = j + 4;
                float dx = px[k]-cx, dy = py[k]-cy, dz = pz[k]-cz;
                float a = dx*dx, b2 = dy*dy, c2 = dz*dz;
                float d = (a + b2) + c2;
                float nd = fminf(dist[k], d); dist[k] = nd;
                bool bt = nd > bm2; bm2 = bt ? nd : bm2; bj2 = bt ? k : bj2;
            }
            {
                int k = j + 6;
                float dx = px[k]-cx, dy = py[k]-cy, dz = pz[k]-cz;
                float a = dx*dx, b2 = dy*dy, c2 = dz*dz;
                float d = (a + b2) + c2;
                float nd = fminf(dist[k], d); dist[k] = nd;
                bool bt = nd > bm3; bm3 = bt ? nd : bm3; bj3 = bt ? k : bj3;
            }
        }
        float bv = bm0; int bj = bj0;
        if (bm1 > bv) { bv = bm1; bj = bj1; }
        if (bm2 > bv) { bv = bm2; bj = bj2; }
        if (bm3 > bv) { bv = bm3; bj = bj3; }
        unsigned mybits = __float_as_uint(bv);
        unsigned vr = mybits;
        { unsigned o = (unsigned)__builtin_amdgcn_update_dpp((int)vr,(int)vr,0x121,0xF,0xF,false); if (o > vr) vr = o; }
        { unsigned o = (unsigned)__builtin_amdgcn_update_dpp((int)vr,(int)vr,0x122,0xF,0xF,false); if (o > vr) vr = o; }
        { unsigned o = (unsigned)__builtin_amdgcn_update_dpp((int)vr,(int)vr,0x124,0xF,0xF,false); if (o > vr) vr = o; }
        { unsigned o = (unsigned)__builtin_amdgcn_update_dpp((int)vr,(int)vr,0x128,0xF,0xF,false); if (o > vr) vr = o; }
        unsigned r0 = (unsigned)__builtin_amdgcn_readlane((int)vr, 0);
        unsigned r1 = (unsigned)__builtin_amdgcn_readlane((int)vr, 16);
        unsigned r2 = (unsigned)__builtin_amdgcn_readlane((int)vr, 32);
        unsigned r3 = (unsigned)__builtin_amdgcn_readlane((int)vr, 48);
        unsigned m01 = (r0 > r1) ? r0 : r1;
        unsigned m23 = (r2 > r3) ? r2 : r3;
        unsigned vmax = (m01 > m23) ? m01 : m23;
        unsigned long long mask = __ballot(mybits == vmax);
        int wl = (int)__builtin_ctzll(mask);
        int gidx = (tid << 3) + bj;
        int sel = __builtin_amdgcn_readlane(gidx, wl);
        unsigned long long key = ((unsigned long long)vmax << 32) | (unsigned)(~sel);
        int buf = t & 1;
        if (lane == 0) red[buf][wave] = key;
        __syncthreads();
        unsigned long long k0 = red[buf][0], k1 = red[buf][1];
        unsigned long long k2 = red[buf][2], k3 = red[buf][3];
        unsigned long long k4 = red[buf][4], k5 = red[buf][5];
        unsigned long long k6 = red[buf][6], k7 = red[buf][7];
        unsigned long long a01 = (k0 > k1) ? k0 : k1;
        unsigned long long a23 = (k2 > k3) ? k2 : k3;
        unsigned long long a45 = (k4 > k5) ? k4 : k5;
        unsigned long long a67 = (k6 > k7) ? k6 : k7;
        unsigned long long b03 = (a01 > a23) ? a01 : a23;
        unsigned long long b47 = (a45 > a67) ? a45 : a67;
        unsigned long long km  = (b03 > b47) ? b03 : b47;
        cur = (int)((~(unsigned)km) & (N_-1));
    }
    __syncthreads();
    for (int i = tid; i < M_; i += 512) {
        int c = selidx[i];
        out_fpsidx[b*M_ + i] = (float)c;
        float4 p = pts[c];
        size_t o3 = (size_t)(b*M_ + i)*3;
        out_newxyz[o3+0] = p.x; out_newxyz[o3+1] = p.y; out_newxyz[o3+2] = p.z;
        ws_newxyz[o3+0] = p.x;  ws_newxyz[o3+1] = p.y;  ws_newxyz[o3+2] = p.z;
    }
}

// ---------------- kNN fallback (round-7 verified, raw xyz) ----------------
__global__ __launch_bounds__(256) void knn_kernel(const float* __restrict__ xyz,
                                                  const float* __restrict__ ws_newxyz,
                                                  int* __restrict__ knn_idx) {
#pragma clang fp contract(off)
    const int lane = threadIdx.x & 63;
    const int q = blockIdx.x * 4 + (threadIdx.x >> 6);
    const int b = q >> 10;
    const float* xb = xyz + (size_t)b * N_ * 3;
    float qx = ws_newxyz[q*3+0], qy = ws_newxyz[q*3+1], qz = ws_newxyz[q*3+2];
    float qq = qx*qx + qy*qy; qq = qq + qz*qz;
    float val[64];
    float m1 = 3.4e38f, m2 = 3.4e38f; int k1 = 0, k2 = 0;
#pragma unroll
    for (int k = 0; k < 64; ++k) {
        int n = (k<<6) + lane;
        float x = xb[n*3+0], y = xb[n*3+1], z = xb[n*3+2];
        float pp = x*x + y*y; pp = pp + z*z;
        float dot = qx*x + qy*y; dot = dot + qz*z;
        float d = (qq + pp) - 2.0f*dot;
        val[k] = d;
        if (d < m1)      { m2 = m1; k2 = k1; m1 = d; k1 = k; }
        else if (d < m2) { m2 = d; k2 = k; }
    }
    unsigned long long consumed = 0ull;
    bool has2 = true;
    unsigned int myOut = 0;
    for (int r = 0; r < 32; ++r) {
        unsigned int u = __float_as_uint(m1);
        u = (u & 0x80000000u) ? ~u : (u | 0x80000000u);
        unsigned long long pk = ((unsigned long long)u << 32) | (unsigned)(lane + (k1<<6));
#pragma unroll
        for (int off = 32; off > 0; off >>= 1) {
            unsigned long long o = __shfl_xor(pk, off);
            pk = (o < pk) ? o : pk;
        }
        unsigned g = (unsigned)pk;
        if (lane == r) myOut = g;
        if (lane == (int)(g & 63u)) {
            consumed |= (1ull << k1);
            if (has2) { m1 = m2; k1 = k2; has2 = false; }
            else {
                m1 = 3.4e38f; k1 = 0;
#pragma unroll
                for (int k = 0; k < 64; ++k) {
                    bool ok = !((consumed >> k) & 1ull) && (val[k] < m1);
                    m1 = ok ? val[k] : m1;
                    k1 = ok ? k : k1;
                }
            }
        }
    }
    if (lane < 32) knn_idx[q*32 + lane] = (int)myOut;
}

// ================== FAST PATH ==================
// pass0: waves 0-1 run knn for the block's 2 queries (verified knn4 logic,
// pts4 now in its own region — no aliasing) while waves 2-3 stage W0B;
// then gather + L0 MFMA + Y0 store + stats0.
__global__ __launch_bounds__(256) void pass0_kernel(
    const float* __restrict__ xyz, const unsigned short* __restrict__ pbf,
    const float* __restrict__ nxw, const float4* __restrict__ pts4,
    const unsigned short* __restrict__ wt0b, const float* __restrict__ cb0,
    float* __restrict__ sb,
    unsigned short* __restrict__ y0b)
{
#pragma clang fp contract(off)
    __shared__ __align__(16) unsigned short XsB[64*104];
    __shared__ __align__(16) unsigned short W0B[64*104];   // reused as store stage
    __shared__ int sidx[64];
    __shared__ float sAcc[64], qAcc[64];
    const int tid = threadIdx.x;
    const int r0 = blockIdx.x * 64;
    const int lane = tid & 63, wv = tid >> 6;
    const int mrow = lane & 15, quad = lane >> 4;

    if (tid < 64) { sAcc[tid] = 0.f; qAcc[tid] = 0.f; }
    if (wv >= 2) {
        const uint4* s = (const uint4*)wt0b;
        for (int i = tid - 128; i < 768; i += 128) {
            int r = i / 12, ch = i - r*12;
            *(uint4*)(W0B + r*104 + ch*8) = s[i];
        }
    } else {
        const int q = blockIdx.x * 2 + wv;
        const int b = q >> 10;
        const float4* pb = pts4 + (size_t)b * N_;
        float qx = nxw[q*3+0], qy = nxw[q*3+1], qz = nxw[q*3+2];
        float qq = qx*qx + qy*qy; qq = qq + qz*qz;
        float val[64];
        float m1 = 3.4e38f, m2 = 3.4e38f; int k1 = 0, k2 = 0;
#pragma unroll
        for (int k = 0; k < 64; ++k) {
            float4 p = pb[(k<<6) + lane];
            float dot = qx*p.x + qy*p.y; dot = dot + qz*p.z;
            float d = (qq + p.w) - 2.0f*dot;
            val[k] = d;
            bool lt1 = d < m1, lt2 = d < m2;
            k2 = lt1 ? k1 : (lt2 ? k : k2);
            m2 = fminf(fmaxf(d, m1), m2);
            k1 = lt1 ? k : k1;
            m1 = fminf(d, m1);
        }
        unsigned long long consumed = 0ull;
        bool has2 = true;
        unsigned int myOut = 0;
        for (int r = 0; r < 32; ++r) {
            unsigned int u = __float_as_uint(m1);
            u = (u & 0x80000000u) ? ~u : (u | 0x80000000u);
            unsigned long long pk = ((unsigned long long)u << 32) | (unsigned)(lane + (k1<<6));
            ROR_MIN(pk, 0x121);
            ROR_MIN(pk, 0x122);
            ROR_MIN(pk, 0x124);
            ROR_MIN(pk, 0x128);
            { unsigned long long o = __shfl_xor(pk, 16); if (o < pk) pk = o; }
            { unsigned long long o = __shfl_xor(pk, 32); if (o < pk) pk = o; }
            unsigned g = (unsigned)pk;
            if (lane == r) myOut = g;
            if (lane == (int)(g & 63u)) {
                consumed |= (1ull << k1);
                if (has2) { m1 = m2; k1 = k2; has2 = false; }
                else {
                    m1 = 3.4e38f; k1 = 0;
#pragma unroll
                    for (int k = 0; k < 64; ++k) {
                        bool ok = !((consumed >> k) & 1ull) && (val[k] < m1);
                        m1 = ok ? val[k] : m1;
                        k1 = ok ? k : k1;
                    }
                }
            }
        }
        if (lane < 32) sidx[wv*32 + lane] = (int)myOut;
    }
    __syncthreads();

    {
        int row = tid >> 2, q4 = tid & 3;
        int gr = r0 + row;
        int qq = gr >> 5, bb = qq >> 10;
        int n = sidx[row];
        const uint4* src = (const uint4*)(pbf + ((size_t)(bb*N_ + n))*64 + q4*16);
        *(uint4*)(XsB + row*104 + q4*16)     = src[0];
        *(uint4*)(XsB + row*104 + q4*16 + 8) = src[1];
        uint4 z;
        if (q4 == 0) {
            float rx = xyz[((size_t)(bb*N_ + n))*3 + 0] - nxw[qq*3 + 0];
            float ry = xyz[((size_t)(bb*N_ + n))*3 + 1] - nxw[qq*3 + 1];
            float rz = xyz[((size_t)(bb*N_ + n))*3 + 2] - nxw[qq*3 + 2];
            z.x = bf16u(rx) | (bf16u(ry) << 16);
            z.y = bf16u(rz);
            z.z = 0; z.w = 0;
        } else { z.x = 0; z.y = 0; z.z = 0; z.w = 0; }
        *(uint4*)(XsB + row*104 + 64 + q4*8) = z;
    }
    __syncthreads();

    const int arow = wv*16 + mrow;
    f32x4 acc0[4];
#pragma unroll
    for (int ct = 0; ct < 4; ++ct) {
        float bv = cb0[ct*16 + mrow];
        acc0[ct] = (f32x4){bv, bv, bv, bv};
    }
#pragma unroll
    for (int kk = 0; kk < 96; kk += 32) {
        bf16x8 a = *(const bf16x8*)(XsB + arow*104 + kk + quad*8);
#pragma unroll
        for (int ct = 0; ct < 4; ++ct) {
            bf16x8 b = *(const bf16x8*)(W0B + (ct*16 + mrow)*104 + kk + quad*8);
            acc0[ct] = __builtin_amdgcn_mfma_f32_16x16x32_bf16(a, b, acc0[ct], 0, 0, 0);
        }
    }
#pragma unroll
    for (int ct = 0; ct < 4; ++ct) {
        f32x4 v = acc0[ct];
        float s = (v.x + v.y) + (v.z + v.w);
        float q = (v.x*v.x + v.y*v.y) + (v.z*v.z + v.w*v.w);
        atomicAdd(&sAcc[ct*16 + mrow], s);
        atomicAdd(&qAcc[ct*16 + mrow], q);
    }
    __syncthreads();   // W0B reads done
    unsigned short* STG = W0B;
    const int rbase = wv*16 + quad*4;
#pragma unroll
    for (int ct = 0; ct < 4; ++ct) {
        int col = ct*16 + mrow;
        f32x4 v = acc0[ct];
        STG[(rbase+0)*72 + col] = (unsigned short)bf16u(v.x);
        STG[(rbase+1)*72 + col] = (unsigned short)bf16u(v.y);
        STG[(rbase+2)*72 + col] = (unsigned short)bf16u(v.z);
        STG[(rbase+3)*72 + col] = (unsigned short)bf16u(v.w);
    }
    __syncthreads();
    for (int i = tid; i < 512; i += 256) {
        int r = i >> 3, c8 = i & 7;
        *(uint4*)(y0b + (size_t)(r0 + r)*64 + c8*8) = *(const uint4*)(STG + r*72 + c8*8);
    }
    int bk = blockIdx.x & 63;
    if (tid < 64) {
        atomicAdd(sb + bk*64 + tid, sAcc[tid]);
        atomicAdd(sb + 4096 + bk*64 + tid, qAcc[tid]);
    }
}

// per-block bn-coefficient recompute, COUT=64, replicating bn_finalize_bk<64>
// exactly (same partial/combine order -> bit-identical coefficients).
__device__ inline void bn64_block(const float* __restrict__ sb,
                                  const float* __restrict__ gamma,
                                  const float* __restrict__ beta,
                                  float* __restrict__ ps, float* __restrict__ pq,
                                  float* __restrict__ bnabL, int tid) {
    const int c = tid & 63;
    const int g = tid >> 6;          // 4 groups of 16 buckets
    float s = 0.f, q = 0.f;
    for (int k = g*16; k < (g+1)*16; ++k) {
        s += sb[k*64 + c];
        q += sb[4096 + k*64 + c];
    }
    ps[tid] = s; pq[tid] = q;
    __syncthreads();
    if (tid < 64) {
        for (int g2 = 1; g2 < 4; ++g2) { s += ps[g2*64 + tid]; q += pq[g2*64 + tid]; }
        const float inv_n = 1.f / (float)RTOT;
        float mu  = s * inv_n;
        float var = q * inv_n - mu*mu;
        float inv = 1.f / sqrtf(var + EPSF);
        float a = gamma[tid] * inv;
        bnabL[tid] = a;
        bnabL[64 + tid] = beta[tid] - mu * a;
    }
    __syncthreads();
}

// pass1: per-block bn0, stream Y0, bn0+relu, L1 MFMA, stats1 (no Y1).
__global__ __launch_bounds__(256) void pass1_kernel(
    const unsigned short* __restrict__ y0b, const unsigned short* __restrict__ wt1b,
    const float* __restrict__ cb1,
    const float* __restrict__ g0, const float* __restrict__ be0,
    const float* __restrict__ sb0, float* __restrict__ sb1)
{
    __shared__ __align__(16) unsigned short W1B[64*72];
    __shared__ float ps[256], pq[256];
    __shared__ float bnab0L[128];
    __shared__ float sAcc[64], qAcc[64];
    const int tid = threadIdx.x;
    const int r0 = blockIdx.x * 64;
    const int lane = tid & 63, wv = tid >> 6;
    const int mrow = lane & 15, quad = lane >> 4;

    {
        const uint4* s = (const uint4*)wt1b;
        for (int i = tid; i < 512; i += 256) {
            int r = i >> 3, ch = i & 7;
            *(uint4*)(W1B + r*72 + ch*8) = s[i];
        }
    }
    if (tid < 64) { sAcc[tid] = 0.f; qAcc[tid] = 0.f; }
    bn64_block(sb0, g0, be0, ps, pq, bnab0L, tid);

    const int gr = r0 + wv*16 + mrow;
    bf16x8 raw0 = *(const bf16x8*)(y0b + (size_t)gr*64 + quad*8);
    bf16x8 raw1 = *(const bf16x8*)(y0b + (size_t)gr*64 + 32 + quad*8);
    bf16x8 a0, a1;
    {
        const float* A = bnab0L + quad*8;
        const float* S = bnab0L + 64 + quad*8;
#pragma unroll
        for (int j = 0; j < 8; ++j) {
            float f = ubf((unsigned short)raw0[j]);
            a0[j] = (short)bf16u(fmaxf(fmaf(A[j], f, S[j]), 0.f));
        }
        const float* A2 = bnab0L + 32 + quad*8;
        const float* S2 = bnab0L + 96 + quad*8;
#pragma unroll
        for (int j = 0; j < 8; ++j) {
            float f = ubf((unsigned short)raw1[j]);
            a1[j] = (short)bf16u(fmaxf(fmaf(A2[j], f, S2[j]), 0.f));
        }
    }

    f32x4 acc[4];
#pragma unroll
    for (int ct = 0; ct < 4; ++ct) {
        float bv = cb1[ct*16 + mrow];
        acc[ct] = (f32x4){bv, bv, bv, bv};
    }
#pragma unroll
    for (int ct = 0; ct < 4; ++ct) {
        bf16x8 b0 = *(const bf16x8*)(W1B + (ct*16 + mrow)*72 + quad*8);
        bf16x8 b1 = *(const bf16x8*)(W1B + (ct*16 + mrow)*72 + 32 + quad*8);
        acc[ct] = __builtin_amdgcn_mfma_f32_16x16x32_bf16(a0, b0, acc[ct], 0, 0, 0);
        acc[ct] = __builtin_amdgcn_mfma_f32_16x16x32_bf16(a1, b1, acc[ct], 0, 0, 0);
    }
#pragma unroll
    for (int ct = 0; ct < 4; ++ct) {
        f32x4 v = acc[ct];
        float s = (v.x + v.y) + (v.z + v.w);
        float q = (v.x*v.x + v.y*v.y) + (v.z*v.z + v.w*v.w);
        atomicAdd(&sAcc[ct*16 + mrow], s);
        atomicAdd(&qAcc[ct*16 + mrow], q);
    }
    __syncthreads();
    int bk = blockIdx.x & 63;
    if (tid < 64) {
        atomicAdd(sb1 + bk*64 + tid, sAcc[tid]);
        atomicAdd(sb1 + 4096 + bk*64 + tid, qAcc[tid]);
    }
}

// pass2: per-block bn0 + bn1, stream Y0, L1 recompute (bit-identical),
// bn1+relu via LDS, L2 MFMA (128 out), stats2 + packed extrema.
__global__ __launch_bounds__(256) void pass2_kernel(
    const unsigned short* __restrict__ y0b,
    const unsigned short* __restrict__ wt1b, const unsigned short* __restrict__ wt2b,
    const float* __restrict__ cb1, const float* __restrict__ cb2,
    const float* __restrict__ g0, const float* __restrict__ be0,
    const float* __restrict__ g1, const float* __restrict__ be1,
    const float* __restrict__ sb0, const float* __restrict__ sb1,
    float* __restrict__ sb2,
    unsigned int* __restrict__ packed)
{
    __shared__ __align__(16) unsigned short W1B[64*72];
    __shared__ __align__(16) unsigned short W2B[128*72];
    __shared__ __align__(16) unsigned short Gb[64*72];
    __shared__ float ps[256], pq[256];
    __shared__ float bnab0L[128], bnab1L[128];
    __shared__ float sAcc[128], qAcc[128];
    __shared__ float mxs[4*128], mns[4*128];
    const int tid = threadIdx.x;
    const int r0 = blockIdx.x * 64;
    const int lane = tid & 63, wv = tid >> 6;
    const int mrow = lane & 15, quad = lane >> 4;

    {
        const uint4* s = (const uint4*)wt1b;
        for (int i = tid; i < 512; i += 256) {
            int r = i >> 3, ch = i & 7;
            *(uint4*)(W1B + r*72 + ch*8) = s[i];
        }
    }
    {
        const uint4* s = (const uint4*)wt2b;
        for (int i = tid; i < 1024; i += 256) {
            int r = i >> 3, ch = i & 7;
            *(uint4*)(W2B + r*72 + ch*8) = s[i];
        }
    }
    if (tid < 128) { sAcc[tid] = 0.f; qAcc[tid] = 0.f; }
    bn64_block(sb0, g0, be0, ps, pq, bnab0L, tid);
    bn64_block(sb1, g1, be1, ps, pq, bnab1L, tid);

    const int gr = r0 + wv*16 + mrow;
    bf16x8 raw0 = *(const bf16x8*)(y0b + (size_t)gr*64 + quad*8);
    bf16x8 raw1 = *(const bf16x8*)(y0b + (size_t)gr*64 + 32 + quad*8);
    bf16x8 a0, a1;
    {
        const float* A = bnab0L + quad*8;
        const float* S = bnab0L + 64 + quad*8;
#pragma unroll
        for (int j = 0; j < 8; ++j) {
            float f = ubf((unsigned short)raw0[j]);
            a0[j] = (short)bf16u(fmaxf(fmaf(A[j], f, S[j]), 0.f));
        }
        const float* A2 = bnab0L + 32 + quad*8;
        const float* S2 = bnab0L + 96 + quad*8;
#pragma unroll
        for (int j = 0; j < 8; ++j) {
            float f = ubf((unsigned short)raw1[j]);
            a1[j] = (short)bf16u(fmaxf(fmaf(A2[j], f, S2[j]), 0.f));
        }
    }

    // L1 recompute (identical inputs/weights -> identical acc1)
    f32x4 acc1[4];
#pragma unroll
    for (int ct = 0; ct < 4; ++ct) {
        float bv = cb1[ct*16 + mrow];
        acc1[ct] = (f32x4){bv, bv, bv, bv};
    }
#pragma unroll
    for (int ct = 0; ct < 4; ++ct) {
        bf16x8 b0 = *(const bf16x8*)(W1B + (ct*16 + mrow)*72 + quad*8);
        bf16x8 b1 = *(const bf16x8*)(W1B + (ct*16 + mrow)*72 + 32 + quad*8);
        acc1[ct] = __builtin_amdgcn_mfma_f32_16x16x32_bf16(a0, b0, acc1[ct], 0, 0, 0);
        acc1[ct] = __builtin_amdgcn_mfma_f32_16x16x32_bf16(a1, b1, acc1[ct], 0, 0, 0);
    }
    const int rbase = wv*16 + quad*4;
#pragma unroll
    for (int ct = 0; ct < 4; ++ct) {
        int col = ct*16 + mrow;
        float a = bnab1L[col], sh = bnab1L[64 + col];
        f32x4 v = acc1[ct];
        Gb[(rbase+0)*72 + col] = (unsigned short)bf16u(fmaxf(fmaf(a, v.x, sh), 0.f));
        Gb[(rbase+1)*72 + col] = (unsigned short)bf16u(fmaxf(fmaf(a, v.y, sh), 0.f));
        Gb[(rbase+2)*72 + col] = (unsigned short)bf16u(fmaxf(fmaf(a, v.z, sh), 0.f));
        Gb[(rbase+3)*72 + col] = (unsigned short)bf16u(fmaxf(fmaf(a, v.w, sh), 0.f));
    }

    const int arow = wv*16 + mrow;
    f32x4 acc[8];
#pragma unroll
    for (int ct = 0; ct < 8; ++ct) {
        float bv = cb2[ct*16 + mrow];
        acc[ct] = (f32x4){bv, bv, bv, bv};
    }
#pragma unroll
    for (int kk = 0; kk < 64; kk += 32) {
        bf16x8 a = *(const bf16x8*)(Gb + arow*72 + kk + quad*8);
#pragma unroll
        for (int ct = 0; ct < 8; ++ct) {
            bf16x8 b = *(const bf16x8*)(W2B + (ct*16 + mrow)*72 + kk + quad*8);
            acc[ct] = __builtin_amdgcn_mfma_f32_16x16x32_bf16(a, b, acc[ct], 0, 0, 0);
        }
    }
#pragma unroll
    for (int ct = 0; ct < 8; ++ct) {
        f32x4 v = acc[ct];
        float s = (v.x + v.y) + (v.z + v.w);
        float q = (v.x*v.x + v.y*v.y) + (v.z*v.z + v.w*v.w);
        atomicAdd(&sAcc[ct*16 + mrow], s);
        atomicAdd(&qAcc[ct*16 + mrow], q);
    }
#pragma unroll
    for (int ct = 0; ct < 8; ++ct) {
        f32x4 v = acc[ct];
        float mx = fmaxf(fmaxf(v.x, v.y), fmaxf(v.z, v.w));
        float mn = fminf(fminf(v.x, v.y), fminf(v.z, v.w));
        { float o = __shfl_xor(mx, 16); mx = fmaxf(mx, o); }
        { float o = __shfl_xor(mn, 16); mn = fminf(mn, o); }
        { float o = __shfl_xor(mx, 32); mx = fmaxf(mx, o); }
        { float o = __shfl_xor(mn, 32); mn = fminf(mn, o); }
        if (quad == 0) {
            mxs[wv*128 + ct*16 + mrow] = mx;
            mns[wv*128 + ct*16 + mrow] = mn;
        }
    }
    __syncthreads();
    {
        int g = tid >> 7, c = tid & 127;
        float mx = fmaxf(mxs[(2*g)*128 + c], mxs[(2*g+1)*128 + c]);
        float mn = fminf(mns[(2*g)*128 + c], mns[(2*g+1)*128 + c]);
        packed[(size_t)(blockIdx.x*2 + g)*128 + c] = (bf16u(mx) << 16) | bf16u(mn);
    }
    int bk = blockIdx.x & 63;
    if (tid < 128) {
        atomicAdd(sb2 + bk*128 + tid, sAcc[tid]);
        atomicAdd(sb2 + 8192 + bk*128 + tid, qAcc[tid]);
    }
}

// final (fast): 256 blocks; per-block bn2 (replicating bn_finalize_bk<128>),
// then BN2+ReLU on 8192 pooled extrema per block.
__global__ __launch_bounds__(256) void final_fast(const unsigned int* __restrict__ packed,
                                                  const float* __restrict__ sb2,
                                                  const float* __restrict__ g2,
                                                  const float* __restrict__ be2,
                                                  float* __restrict__ out_np) {
    __shared__ float ps[256], pq[256];
    __shared__ float bn[256];
    const int tid = threadIdx.x;
    const int c = tid & 127;
    const int g = tid >> 7;          // 2 groups of 32 buckets
    float s = 0.f, q = 0.f;
    for (int k = g*32; k < (g+1)*32; ++k) {
        s += sb2[k*128 + c];
        q += sb2[8192 + k*128 + c];
    }
    ps[tid] = s; pq[tid] = q;
    __syncthreads();
    if (tid < 128) {
        s += ps[128 + tid]; q += pq[128 + tid];
        const float inv_n = 1.f / (float)RTOT;
        float mu  = s * inv_n;
        float var = q * inv_n - mu*mu;
        float inv = 1.f / sqrtf(var + EPSF);
        float a = g2[tid] * inv;
        bn[tid] = a;
        bn[128 + tid] = be2[tid] - mu * a;
    }
    __syncthreads();
    const size_t base = (size_t)blockIdx.x * 8192;
#pragma unroll 4
    for (int j = 0; j < 32; ++j) {
        size_t idx = base + j*256 + tid;
        int cc = (int)(idx & 127);
        float a = bn[cc], sh = bn[128 + cc];
        unsigned p = packed[idx];
        float mx = __uint_as_float(p & 0xFFFF0000u);
        float mn = __uint_as_float(p << 16);
        float x = (a >= 0.f) ? mx : mn;
        out_np[idx] = fmaxf(fmaf(a, x, sh), 0.f);
    }
}

// ================== FALLBACK PATH (recompute, verified) ==============
template<int DEPTH>
__global__ __launch_bounds__(256) void mlp_pass(
    const float* __restrict__ xyz, const float* __restrict__ points,
    const float* __restrict__ nxw, const int* __restrict__ kidx,
    const unsigned short* __restrict__ wt0b, const unsigned short* __restrict__ wt1b,
    const unsigned short* __restrict__ wt2b,
    const float* __restrict__ cb0, const float* __restrict__ cb1,
    const float* __restrict__ cb2,
    const float* __restrict__ bnab0, const float* __restrict__ bnab1,
    float* __restrict__ statS, float* __restrict__ statQ,
    unsigned int* __restrict__ packed)
{
    __shared__ __align__(16) unsigned short XsB[64*104];
    __shared__ __align__(16) unsigned short W0B[64*104];
    __shared__ __align__(16) unsigned short W1B[(DEPTH>=2) ? 64*72 : 8];
    __shared__ __align__(16) unsigned short W2B[(DEPTH==3) ? 128*72 : 8];
    __shared__ __align__(16) unsigned short Gb [(DEPTH>=2) ? 64*72 : 8];
    __shared__ float sAcc[128], qAcc[128];
    __shared__ float mxs[(DEPTH==3) ? 4*128 : 1];
    __shared__ float mns[(DEPTH==3) ? 4*128 : 1];

    const int tid = threadIdx.x;
    const int r0 = blockIdx.x * 64;
    const int lane = tid & 63, wv = tid >> 6;
    const int mrow = lane & 15, quad = lane >> 4;

    {
        const uint4* s = (const uint4*)wt0b;
        for (int i = tid; i < 768; i += 256) {
            int r = i / 12, ch = i - r*12;
            *(uint4*)(W0B + r*104 + ch*8) = s[i];
        }
    }
    if constexpr (DEPTH >= 2) {
        const uint4* s = (const uint4*)wt1b;
        for (int i = tid; i < 512; i += 256) {
            int r = i >> 3, ch = i & 7;
            *(uint4*)(W1B + r*72 + ch*8) = s[i];
        }
    }
    if constexpr (DEPTH == 3) {
        const uint4* s = (const uint4*)wt2b;
        for (int i = tid; i < 1024; i += 256) {
            int r = i >> 3, ch = i & 7;
            *(uint4*)(W2B + r*72 + ch*8) = s[i];
        }
    }
    if (tid < 128) { sAcc[tid] = 0.f; qAcc[tid] = 0.f; }

    for (int i = tid; i < 64*96; i += 256) {
        int r = i / 96, c = i - r*96;
        int gr = r0 + r;
        int q = gr >> 5;
        int n = kidx[gr];
        int bb = q >> 10;
        float v = 0.f;
        if (c < 64)      v = points[((size_t)(bb*N_ + n))*64 + c];
        else if (c < 67) v = xyz[((size_t)(bb*N_ + n))*3 + (c-64)] - nxw[q*3 + (c-64)];
        XsB[r*104 + c] = (unsigned short)bf16u(v);
    }
    __syncthreads();

    const int arow = wv*16 + mrow;
    f32x4 acc0[4];
#pragma unroll
    for (int ct = 0; ct < 4; ++ct) {
        float bv = cb0[ct*16 + mrow];
        acc0[ct] = (f32x4){bv, bv, bv, bv};
    }
#pragma unroll
    for (int kk = 0; kk < 96; kk += 32) {
        bf16x8 a = *(const bf16x8*)(XsB + arow*104 + kk + quad*8);
#pragma unroll
        for (int ct = 0; ct < 4; ++ct) {
            bf16x8 b = *(const bf16x8*)(W0B + (ct*16 + mrow)*104 + kk + quad*8);
            acc0[ct] = __builtin_amdgcn_mfma_f32_16x16x32_bf16(a, b, acc0[ct], 0, 0, 0);
        }
    }

    if constexpr (DEPTH == 1) {
#pragma unroll
        for (int ct = 0; ct < 4; ++ct) {
            f32x4 v = acc0[ct];
            float s = (v.x + v.y) + (v.z + v.w);
            float q = (v.x*v.x + v.y*v.y) + (v.z*v.z + v.w*v.w);
            atomicAdd(&sAcc[ct*16 + mrow], s);
            atomicAdd(&qAcc[ct*16 + mrow], q);
        }
        __syncthreads();
        if (tid < 64) { atomicAdd(statS + tid, sAcc[tid]); atomicAdd(statQ + tid, qAcc[tid]); }
        return;
    } else {
        const int rbase = wv*16 + quad*4;
#pragma unroll
        for (int ct = 0; ct < 4; ++ct) {
            int col = ct*16 + mrow;
            float a = bnab0[col], sh = bnab0[64 + col];
            f32x4 v = acc0[ct];
            Gb[(rbase+0)*72 + col] = (unsigned short)bf16u(fmaxf(fmaf(a, v.x, sh), 0.f));
            Gb[(rbase+1)*72 + col] = (unsigned short)bf16u(fmaxf(fmaf(a, v.y, sh), 0.f));
            Gb[(rbase+2)*72 + col] = (unsigned short)bf16u(fmaxf(fmaf(a, v.z, sh), 0.f));
            Gb[(rbase+3)*72 + col] = (unsigned short)bf16u(fmaxf(fmaf(a, v.w, sh), 0.f));
        }
        f32x4 acc1[4];
#pragma unroll
        for (int ct = 0; ct < 4; ++ct) {
            float bv = cb1[ct*16 + mrow];
            acc1[ct] = (f32x4){bv, bv, bv, bv};
        }
#pragma unroll
        for (int kk = 0; kk < 64; kk += 32) {
            bf16x8 a = *(const bf16x8*)(Gb + arow*72 + kk + quad*8);
#pragma unroll
            for (int ct = 0; ct < 4; ++ct) {
                bf16x8 b = *(const bf16x8*)(W1B + (ct*16 + mrow)*72 + kk + quad*8);
                acc1[ct] = __builtin_amdgcn_mfma_f32_16x16x32_bf16(a, b, acc1[ct], 0, 0, 0);
            }
        }
        if constexpr (DEPTH == 2) {
#pragma unroll
            for (int ct = 0; ct < 4; ++ct) {
                f32x4 v = acc1[ct];
                float s = (v.x + v.y) + (v.z + v.w);
                float q = (v.x*v.x + v.y*v.y) + (v.z*v.z + v.w*v.w);
                atomicAdd(&sAcc[ct*16 + mrow], s);
                atomicAdd(&qAcc[ct*16 + mrow], q);
            }
            __syncthreads();
            if (tid < 64) { atomicAdd(statS + tid, sAcc[tid]); atomicAdd(statQ + tid, qAcc[tid]); }
            return;
        } else {
#pragma unroll
            for (int ct = 0; ct < 4; ++ct) {
                int col = ct*16 + mrow;
                float a = bnab1[col], sh = bnab1[64 + col];
                f32x4 v = acc1[ct];
                Gb[(rbase+0)*72 + col] = (unsigned short)bf16u(fmaxf(fmaf(a, v.x, sh), 0.f));
                Gb[(rbase+1)*72 + col] = (unsigned short)bf16u(fmaxf(fmaf(a, v.y, sh), 0.f));
                Gb[(rbase+2)*72 + col] = (unsigned short)bf16u(fmaxf(fmaf(a, v.z, sh), 0.f));
                Gb[(rbase+3)*72 + col] = (unsigned short)bf16u(fmaxf(fmaf(a, v.w, sh), 0.f));
            }
            f32x4 acc2[8];
#pragma unroll
            for (int ct = 0; ct < 8; ++ct) {
                float bv = cb2[ct*16 + mrow];
                acc2[ct] = (f32x4){bv, bv, bv, bv};
            }
#pragma unroll
            for (int kk = 0; kk < 64; kk += 32) {
                bf16x8 a = *(const bf16x8*)(Gb + arow*72 + kk + quad*8);
#pragma unroll
                for (int ct = 0; ct < 8; ++ct) {
                    bf16x8 b = *(const bf16x8*)(W2B + (ct*16 + mrow)*72 + kk + quad*8);
                    acc2[ct] = __builtin_amdgcn_mfma_f32_16x16x32_bf16(a, b, acc2[ct], 0, 0, 0);
                }
            }
#pragma unroll
            for (int ct = 0; ct < 8; ++ct) {
                f32x4 v = acc2[ct];
                float s = (v.x + v.y) + (v.z + v.w);
                float q = (v.x*v.x + v.y*v.y) + (v.z*v.z + v.w*v.w);
                atomicAdd(&sAcc[ct*16 + mrow], s);
                atomicAdd(&qAcc[ct*16 + mrow], q);
            }
#pragma unroll
            for (int ct = 0; ct < 8; ++ct) {
                f32x4 v = acc2[ct];
                float mx = fmaxf(fmaxf(v.x, v.y), fmaxf(v.z, v.w));
                float mn = fminf(fminf(v.x, v.y), fminf(v.z, v.w));
                { float o = __shfl_xor(mx, 16); mx = fmaxf(mx, o); }
                { float o = __shfl_xor(mn, 16); mn = fminf(mn, o); }
                { float o = __shfl_xor(mx, 32); mx = fmaxf(mx, o); }
                { float o = __shfl_xor(mn, 32); mn = fminf(mn, o); }
                if (quad == 0) {
                    mxs[wv*128 + ct*16 + mrow] = mx;
                    mns[wv*128 + ct*16 + mrow] = mn;
                }
            }
            __syncthreads();
            {
                int g = tid >> 7, c = tid & 127;
                float mx = fmaxf(mxs[(2*g)*128 + c], mxs[(2*g+1)*128 + c]);
                float mn = fminf(mns[(2*g)*128 + c], mns[(2*g+1)*128 + c]);
                packed[(size_t)(blockIdx.x*2 + g)*128 + c] = (bf16u(mx) << 16) | bf16u(mn);
            }
            if (tid < 128) { atomicAdd(statS + tid, sAcc[tid]); atomicAdd(statQ + tid, qAcc[tid]); }
        }
    }
}

template<int COUT>
__global__ void bn_finalize(const float* __restrict__ stat_s, const float* __restrict__ stat_q,
                            const float* __restrict__ gamma, const float* __restrict__ beta,
                            float* __restrict__ bnab) {
    int c = threadIdx.x;
    if (c < COUT) {
        const float inv_n = 1.f / (float)RTOT;
        float mu  = stat_s[c] * inv_n;
        float var = stat_q[c] * inv_n - mu*mu;
        float inv = 1.f / sqrtf(var + EPSF);
        float a = gamma[c] * inv;
        bnab[c] = a;
        bnab[COUT + c] = beta[c] - mu * a;
    }
}

__global__ __launch_bounds__(256) void final_out(const unsigned int* __restrict__ packed,
                                                 const float* __restrict__ bnab2,
                                                 float* __restrict__ out_np) {
    int idx = blockIdx.x*256 + threadIdx.x;
    int c = idx & 127;
    float a = bnab2[c], sh = bnab2[128 + c];
    unsigned p = packed[idx];
    float mx = __uint_as_float(p & 0xFFFF0000u);
    float mn = __uint_as_float(p << 16);
    float x = (a >= 0.f) ? mx : mn;
    out_np[idx] = fmaxf(fmaf(a, x, sh), 0.f);
}

extern "C" void kernel_launch(void* const* d_in, const int* in_sizes, int n_in,
                              void* d_out, int out_size, void* d_ws, size_t ws_size,
                              hipStream_t stream) {
    const float* xyz    = (const float*)d_in[0];
    const float* points = (const float*)d_in[1];
    const float* W0 = (const float*)d_in[2];
    const float* b0 = (const float*)d_in[3];
    const float* g0 = (const float*)d_in[4];
    const float* be0= (const float*)d_in[5];
    const float* W1 = (const float*)d_in[6];
    const float* b1 = (const float*)d_in[7];
    const float* g1 = (const float*)d_in[8];
    const float* be1= (const float*)d_in[9];
    const float* W2 = (const float*)d_in[10];
    const float* b2 = (const float*)d_in[11];
    const float* g2 = (const float*)d_in[12];
    const float* be2= (const float*)d_in[13];

    float* ws  = (float*)d_ws;
    float* out = (float*)d_out;
    float* out_newxyz = out;                        // 49152
    float* out_np     = out + 49152;                // 2097152
    float* out_fpsidx = out + 49152 + 2097152;      // 16384

    unsigned short* wt0b = (unsigned short*)(ws + WT0B_OFF);
    unsigned short* wt1b = (unsigned short*)(ws + WT1B_OFF);
    unsigned short* wt2b = (unsigned short*)(ws + WT2B_OFF);
    float* s0 = ws + ST_OFF;        float* q0 = s0 + 64;
    float* s1 = q0 + 64;            float* q1 = s1 + 64;
    float* s2 = q1 + 64;            float* q2 = s2 + 128;
    float* bnab0 = ws + BN_OFF;     float* bnab1 = bnab0 + 128;  float* bnab2 = bnab1 + 128;
    float* nxw   = ws + NXW_OFF;
    int*   kidx  = (int*)(ws + KIDX_OFF);
    unsigned int* packed = (unsigned int*)(ws + PK_OFF);
    unsigned short* y0b = (unsigned short*)(ws + Y0B_OFF);
    unsigned short* pbf = (unsigned short*)(ws + PBF_OFF);
    float4* pts4 = (float4*)(ws + PTS4_OFF);        // own region — no Y0 aliasing
    float* sb0 = ws + SB0_OFF;
    float* sb1 = ws + SB1_OFF;
    float* sb2 = ws + SB2_OFF;

    int fast = (ws_size >= WS_FAST_BYTES) ? 1 : 0;

    fps_kernel<<<fast ? 1057 : 17, 512, 0, stream>>>(xyz, out_newxyz, out_fpsidx, nxw,
        fast ? pts4 : nullptr, W0, W1, W2, points, ws, fast);

    if (fast) {
        pass0_kernel<<<RTOT/64, 256, 0, stream>>>(xyz, pbf, nxw, pts4, wt0b, b0, sb0, y0b);
        pass1_kernel<<<RTOT/64, 256, 0, stream>>>(y0b, wt1b, b1, g0, be0, sb0, sb1);
        pass2_kernel<<<RTOT/64, 256, 0, stream>>>(y0b, wt1b, wt2b, b1, b2,
                                                  g0, be0, g1, be1, sb0, sb1, sb2, packed);
        final_fast<<<256, 256, 0, stream>>>(packed, sb2, g2, be2, out_np);
    } else {
        knn_kernel<<<(B_*M_)/4, 256, 0, stream>>>(xyz, nxw, kidx);
        mlp_pass<1><<<RTOT/64, 256, 0, stream>>>(xyz, points, nxw, kidx, wt0b, wt1b, wt2b,
            b0, b1, b2, nullptr, nullptr, s0, q0, nullptr);
        bn_finalize<64><<<1, 64, 0, stream>>>(s0, q0, g0, be0, bnab0);
        mlp_pass<2><<<RTOT/64, 256, 0, stream>>>(xyz, points, nxw, kidx, wt0b, wt1b, wt2b,
            b0, b1, b2, bnab0, nullptr, s1, q1, nullptr);
        bn_finalize<64><<<1, 64, 0, stream>>>(s1, q1, g1, be1, bnab1);
        mlp_pass<3><<<RTOT/64, 256, 0, stream>>>(xyz, points, nxw, kidx, wt0b, wt1b, wt2b,
            b0, b1, b2, bnab0, bnab1, s2, q2, packed);
        bn_finalize<128><<<1, 128, 0, stream>>>(s2, q2, g2, be2, bnab2);
        final_out<<<(B_*M_*128)/256, 256, 0, stream>>>(packed, bnab2, out_np);
    }
}

// Round 12
// 1299.304 us; speedup vs baseline: 1.1410x; 1.1410x over previous
//
#include <hip/hip_runtime.h>
#include <math.h>

#define B_ 16
#define N_ 4096
#define D_ 64
#define M_ 1024
#define K_ 32
#define RTOT (B_*M_*K_)          // 524288 rows
#define EPSF 1e-5f

// ---------------- ws layout (float units)
#define WT0B_OFF  0              // bf16 W0 perm [64 out][96 k] = 3072 f
#define WT1B_OFF  3072           // bf16 [64][64] = 2048 f
#define WT2B_OFF  5120           // bf16 [128][64] = 4096 f
#define ST_OFF    9216           // fallback stats s/q = 512
#define BN_OFF    9728           // ab0[128] ab1[128] ab2[256] = 512
#define NXW_OFF   10240          // new_xyz f32 [16384*3]
#define KIDX_OFF  59392          // knn idx int [524288]
#define PK_OFF    583680         // packed bf16 (max,min) [16384*128] uint32
#define Y0B_OFF   2680832        // bf16 Y0 raw [524288*64] = 16777216 f
#define Y1B_OFF   19458048       // bf16 Y1 raw [524288*64] = 16777216 f
// stat buckets (fast path only): 64 buckets, s then q per layer
#define SB0_OFF   36235264       // [64][64]s + [64][64]q = 8192
#define SB1_OFF   (SB0_OFF + 8192)
#define SB2_OFF   (SB1_OFF + 8192)   // [64][128]s + [64][128]q = 16384
#define WS_FAST_BYTES ((unsigned long long)(SB2_OFF + 16384) * 4ull)

typedef __attribute__((ext_vector_type(8))) short bf16x8;
typedef __attribute__((ext_vector_type(4))) float f32x4;

__device__ inline unsigned bf16u(float x) {
    unsigned u = __float_as_uint(x);
    return (u + 0x7FFFu + ((u >> 16) & 1u)) >> 16;   // RN-even
}
__device__ inline float ubf(unsigned short h) {
    return __uint_as_float(((unsigned)h) << 16);
}

// ---------------- prep: block 0 = weights+st; blocks 1..16 zero buckets ----
__global__ void prep_kernel(const float* __restrict__ W0, const float* __restrict__ W1,
                            const float* __restrict__ W2, float* __restrict__ ws,
                            int zero_sb) {
    int tid = threadIdx.x;
    if (blockIdx.x > 0) {
        if (zero_sb) {
            float* sb = ws + SB0_OFF + (blockIdx.x - 1) * 2048;
            for (int i = tid; i < 2048; i += 256) sb[i] = 0.f;
        }
        return;
    }
    unsigned short* wt0b = (unsigned short*)(ws + WT0B_OFF);
    unsigned short* wt1b = (unsigned short*)(ws + WT1B_OFF);
    unsigned short* wt2b = (unsigned short*)(ws + WT2B_OFF);
    float* st = ws + ST_OFF;
    for (int i = tid; i < 512; i += 256) st[i] = 0.f;
    for (int i = tid; i < 64*96; i += 256) {
        int o = i / 96, k = i - o*96;
        float w = 0.f;
        if (k < 64)      w = W0[o*67 + 3 + k];
        else if (k < 67) w = W0[o*67 + (k - 64)];
        wt0b[i] = (unsigned short)bf16u(w);
    }
    for (int i = tid; i < 64*64; i += 256)  wt1b[i] = (unsigned short)bf16u(W1[i]);
    for (int i = tid; i < 128*64; i += 256) wt2b[i] = (unsigned short)bf16u(W2[i]);
}

// ---------------- FPS: 256 thr, 4 waves — verified 613us config ----------
__global__ __launch_bounds__(256) void fps_kernel(const float* __restrict__ xyz,
                                                  float* __restrict__ out_newxyz,
                                                  float* __restrict__ out_fpsidx,
                                                  float* __restrict__ ws_newxyz) {
#pragma clang fp contract(off)
    __shared__ float4 pts[N_];
    __shared__ int selidx[M_];
    __shared__ unsigned long long red[2][4];
    const int b = blockIdx.x;
    const int tid = threadIdx.x;
    const int lane = tid & 63, wave = tid >> 6;
    const float* xb = xyz + (size_t)b * N_ * 3;
    for (int i = tid; i < N_; i += 256)
        pts[i] = make_float4(xb[i*3+0], xb[i*3+1], xb[i*3+2], 0.f);
    __syncthreads();
    float px[16], py[16], pz[16], dist[16];
#pragma unroll
    for (int j = 0; j < 16; ++j) {
        float4 p = pts[(tid << 4) + j];
        px[j] = p.x; py[j] = p.y; pz[j] = p.z;
        dist[j] = 3.4e38f;
    }
    int cur = N_/2;
    for (int t = 0; t < M_; ++t) {
        if (tid == (t & 255)) selidx[t] = cur;
        if (t == M_-1) break;
        float4 c4 = pts[cur];
        float cx = c4.x, cy = c4.y, cz = c4.z;
        float bm0 = -1.f, bm1 = -1.f, bm2 = -1.f, bm3 = -1.f;
        int bj0 = 0, bj1 = 4, bj2 = 8, bj3 = 12;
#pragma unroll
        for (int j = 0; j < 4; ++j) {
            {
                float dx = px[j]-cx, dy = py[j]-cy, dz = pz[j]-cz;
                float a = dx*dx, b2 = dy*dy, c2 = dz*dz;
                float d = (a + b2) + c2;
                float nd = fminf(dist[j], d); dist[j] = nd;
                bool bt = nd > bm0; bm0 = bt ? nd : bm0; bj0 = bt ? j : bj0;
            }
            {
                int k = j + 4;
                float dx = px[k]-cx, dy = py[k]-cy, dz = pz[k]-cz;
                float a = dx*dx, b2 = dy*dy, c2 = dz*dz;
                float d = (a + b2) + c2;
                float nd = fminf(dist[k], d); dist[k] = nd;
                bool bt = nd > bm1; bm1 = bt ? nd : bm1; bj1 = bt ? k : bj1;
            }
            {
                int k = j + 8;
                float dx = px[k]-cx, dy = py[k]-cy, dz = pz[k]-cz;
                float a = dx*dx, b2 = dy*dy, c2 = dz*dz;
                float d = (a + b2) + c2;
                float nd = fminf(dist[k], d); dist[k] = nd;
                bool bt = nd > bm2; bm2 = bt ? nd : bm2; bj2 = bt ? k : bj2;
            }
            {
                int k = j + 12;
                float dx = px[k]-cx, dy = py[k]-cy, dz = pz[k]-cz;
                float a = dx*dx, b2 = dy*dy, c2 = dz*dz;
                float d = (a + b2) + c2;
                float nd = fminf(dist[k], d); dist[k] = nd;
                bool bt = nd > bm3; bm3 = bt ? nd : bm3; bj3 = bt ? k : bj3;
            }
        }
        float bv = bm0; int bj = bj0;
        if (bm1 > bv) { bv = bm1; bj = bj1; }
        if (bm2 > bv) { bv = bm2; bj = bj2; }
        if (bm3 > bv) { bv = bm3; bj = bj3; }
        unsigned mybits = __float_as_uint(bv);
        unsigned vr = mybits;
        { unsigned o = (unsigned)__builtin_amdgcn_update_dpp((int)vr,(int)vr,0x121,0xF,0xF,false); if (o > vr) vr = o; }
        { unsigned o = (unsigned)__builtin_amdgcn_update_dpp((int)vr,(int)vr,0x122,0xF,0xF,false); if (o > vr) vr = o; }
        { unsigned o = (unsigned)__builtin_amdgcn_update_dpp((int)vr,(int)vr,0x124,0xF,0xF,false); if (o > vr) vr = o; }
        { unsigned o = (unsigned)__builtin_amdgcn_update_dpp((int)vr,(int)vr,0x128,0xF,0xF,false); if (o > vr) vr = o; }
        unsigned r0 = (unsigned)__builtin_amdgcn_readlane((int)vr, 0);
        unsigned r1 = (unsigned)__builtin_amdgcn_readlane((int)vr, 16);
        unsigned r2 = (unsigned)__builtin_amdgcn_readlane((int)vr, 32);
        unsigned r3 = (unsigned)__builtin_amdgcn_readlane((int)vr, 48);
        unsigned m01 = (r0 > r1) ? r0 : r1;
        unsigned m23 = (r2 > r3) ? r2 : r3;
        unsigned vmax = (m01 > m23) ? m01 : m23;
        unsigned long long mask = __ballot(mybits == vmax);
        int wl = (int)__builtin_ctzll(mask);
        int gidx = (tid << 4) + bj;
        int sel = __builtin_amdgcn_readlane(gidx, wl);
        unsigned long long key = ((unsigned long long)vmax << 32) | (unsigned)(~sel);
        int buf = t & 1;
        if (lane == 0) red[buf][wave] = key;
        __syncthreads();
        unsigned long long k0 = red[buf][0], k1 = red[buf][1];
        unsigned long long k2 = red[buf][2], k3 = red[buf][3];
        unsigned long long km01 = (k0 > k1) ? k0 : k1;
        unsigned long long km23 = (k2 > k3) ? k2 : k3;
        unsigned long long km   = (km01 > km23) ? km01 : km23;
        cur = (int)((~(unsigned)km) & (N_-1));
    }
    __syncthreads();
    for (int i = tid; i < M_; i += 256) {
        int c = selidx[i];
        out_fpsidx[b*M_ + i] = (float)c;
        float4 p = pts[c];
        size_t o3 = (size_t)(b*M_ + i)*3;
        out_newxyz[o3+0] = p.x; out_newxyz[o3+1] = p.y; out_newxyz[o3+2] = p.z;
        ws_newxyz[o3+0] = p.x;  ws_newxyz[o3+1] = p.y;  ws_newxyz[o3+2] = p.z;
    }
}

// ---------------- kNN: lazy top-2 + consumed bitmask (verified) ----------
__global__ __launch_bounds__(256) void knn_kernel(const float* __restrict__ xyz,
                                                  const float* __restrict__ ws_newxyz,
                                                  int* __restrict__ knn_idx) {
#pragma clang fp contract(off)
    const int lane = threadIdx.x & 63;
    const int q = blockIdx.x * 4 + (threadIdx.x >> 6);
    const int b = q >> 10;
    const float* xb = xyz + (size_t)b * N_ * 3;
    float qx = ws_newxyz[q*3+0], qy = ws_newxyz[q*3+1], qz = ws_newxyz[q*3+2];
    float qq = qx*qx + qy*qy; qq = qq + qz*qz;
    float val[64];
    float m1 = 3.4e38f, m2 = 3.4e38f; int k1 = 0, k2 = 0;
#pragma unroll
    for (int k = 0; k < 64; ++k) {
        int n = (k<<6) + lane;
        float x = xb[n*3+0], y = xb[n*3+1], z = xb[n*3+2];
        float pp = x*x + y*y; pp = pp + z*z;
        float dot = qx*x + qy*y; dot = dot + qz*z;
        float d = (qq + pp) - 2.0f*dot;
        val[k] = d;
        if (d < m1)      { m2 = m1; k2 = k1; m1 = d; k1 = k; }
        else if (d < m2) { m2 = d; k2 = k; }
    }
    unsigned long long consumed = 0ull;
    bool has2 = true;
    unsigned int myOut = 0;
    for (int r = 0; r < 32; ++r) {
        unsigned int u = __float_as_uint(m1);
        u = (u & 0x80000000u) ? ~u : (u | 0x80000000u);   // orderable key
        unsigned long long pk = ((unsigned long long)u << 32) | (unsigned)(lane + (k1<<6));
#pragma unroll
        for (int off = 32; off > 0; off >>= 1) {
            unsigned long long o = __shfl_xor(pk, off);
            pk = (o < pk) ? o : pk;
        }
        unsigned g = (unsigned)pk;
        if (lane == r) myOut = g;
        if (lane == (int)(g & 63u)) {
            consumed |= (1ull << k1);
            if (has2) { m1 = m2; k1 = k2; has2 = false; }
            else {
                m1 = 3.4e38f; k1 = 0;
#pragma unroll
                for (int k = 0; k < 64; ++k) {
                    bool ok = !((consumed >> k) & 1ull) && (val[k] < m1);
                    m1 = ok ? val[k] : m1;
                    k1 = ok ? k : k1;
                }
            }
        }
    }
    if (lane < 32) knn_idx[q*32 + lane] = (int)myOut;
}

// ================== FAST PATH (stored intermediates, bucketed stats) =======
// pass0: gather X0, L0 MFMA, store raw Y0 bf16, stats0 -> bucket blockIdx&63.
__global__ __launch_bounds__(256) void pass0_kernel(
    const float* __restrict__ xyz, const float* __restrict__ points,
    const float* __restrict__ nxw, const int* __restrict__ kidx,
    const unsigned short* __restrict__ wt0b, const float* __restrict__ cb0,
    float* __restrict__ sb,           // [64][64]s + [64][64]q
    unsigned short* __restrict__ y0b)
{
    __shared__ __align__(16) unsigned short XsB[64*104];
    __shared__ __align__(16) unsigned short W0B[64*104];   // reused as store stage
    __shared__ int sidx[64];
    __shared__ float sAcc[64], qAcc[64];
    const int tid = threadIdx.x;
    const int r0 = blockIdx.x * 64;
    const int lane = tid & 63, wv = tid >> 6;
    const int mrow = lane & 15, quad = lane >> 4;

    if (tid < 64) { sidx[tid] = kidx[r0 + tid]; sAcc[tid] = 0.f; qAcc[tid] = 0.f; }
    {
        const uint4* s = (const uint4*)wt0b;
        for (int i = tid; i < 768; i += 256) {
            int r = i / 12, ch = i - r*12;
            *(uint4*)(W0B + r*104 + ch*8) = s[i];
        }
    }
    __syncthreads();

    {
        int row = tid >> 2, q4 = tid & 3;
        int gr = r0 + row;
        int qq = gr >> 5, bb = qq >> 10;
        int n = sidx[row];
        const float4* src = (const float4*)(points + ((size_t)(bb*N_ + n))*64 + q4*16);
        float4 f0 = src[0], f1 = src[1], f2 = src[2], f3 = src[3];
        uint4 u0, u1;
        u0.x = bf16u(f0.x) | (bf16u(f0.y) << 16);
        u0.y = bf16u(f0.z) | (bf16u(f0.w) << 16);
        u0.z = bf16u(f1.x) | (bf16u(f1.y) << 16);
        u0.w = bf16u(f1.z) | (bf16u(f1.w) << 16);
        u1.x = bf16u(f2.x) | (bf16u(f2.y) << 16);
        u1.y = bf16u(f2.z) | (bf16u(f2.w) << 16);
        u1.z = bf16u(f3.x) | (bf16u(f3.y) << 16);
        u1.w = bf16u(f3.z) | (bf16u(f3.w) << 16);
        *(uint4*)(XsB + row*104 + q4*16)     = u0;
        *(uint4*)(XsB + row*104 + q4*16 + 8) = u1;
        uint4 z;
        if (q4 == 0) {
            float rx = xyz[((size_t)(bb*N_ + n))*3 + 0] - nxw[qq*3 + 0];
            float ry = xyz[((size_t)(bb*N_ + n))*3 + 1] - nxw[qq*3 + 1];
            float rz = xyz[((size_t)(bb*N_ + n))*3 + 2] - nxw[qq*3 + 2];
            z.x = bf16u(rx) | (bf16u(ry) << 16);
            z.y = bf16u(rz);
            z.z = 0; z.w = 0;
        } else { z.x = 0; z.y = 0; z.z = 0; z.w = 0; }
        *(uint4*)(XsB + row*104 + 64 + q4*8) = z;
    }
    __syncthreads();

    const int arow = wv*16 + mrow;
    f32x4 acc0[4];
#pragma unroll
    for (int ct = 0; ct < 4; ++ct) {
        float bv = cb0[ct*16 + mrow];
        acc0[ct] = (f32x4){bv, bv, bv, bv};
    }
#pragma unroll
    for (int kk = 0; kk < 96; kk += 32) {
        bf16x8 a = *(const bf16x8*)(XsB + arow*104 + kk + quad*8);
#pragma unroll
        for (int ct = 0; ct < 4; ++ct) {
            bf16x8 b = *(const bf16x8*)(W0B + (ct*16 + mrow)*104 + kk + quad*8);
            acc0[ct] = __builtin_amdgcn_mfma_f32_16x16x32_bf16(a, b, acc0[ct], 0, 0, 0);
        }
    }
#pragma unroll
    for (int ct = 0; ct < 4; ++ct) {
        f32x4 v = acc0[ct];
        float s = (v.x + v.y) + (v.z + v.w);
        float q = (v.x*v.x + v.y*v.y) + (v.z*v.z + v.w*v.w);
        atomicAdd(&sAcc[ct*16 + mrow], s);
        atomicAdd(&qAcc[ct*16 + mrow], q);
    }
    __syncthreads();   // W0B reads done
    unsigned short* STG = W0B;
    const int rbase = wv*16 + quad*4;
#pragma unroll
    for (int ct = 0; ct < 4; ++ct) {
        int col = ct*16 + mrow;
        f32x4 v = acc0[ct];
        STG[(rbase+0)*72 + col] = (unsigned short)bf16u(v.x);
        STG[(rbase+1)*72 + col] = (unsigned short)bf16u(v.y);
        STG[(rbase+2)*72 + col] = (unsigned short)bf16u(v.z);
        STG[(rbase+3)*72 + col] = (unsigned short)bf16u(v.w);
    }
    __syncthreads();
    for (int i = tid; i < 512; i += 256) {
        int r = i >> 3, c8 = i & 7;
        *(uint4*)(y0b + (size_t)(r0 + r)*64 + c8*8) = *(const uint4*)(STG + r*72 + c8*8);
    }
    int bk = blockIdx.x & 63;
    if (tid < 64) {
        atomicAdd(sb + bk*64 + tid, sAcc[tid]);
        atomicAdd(sb + 4096 + bk*64 + tid, qAcc[tid]);
    }
}

// pass1: stream Y0, bn0+relu in-register, L1 MFMA, store raw Y1, stats1.
__global__ __launch_bounds__(256) void pass1_kernel(
    const unsigned short* __restrict__ y0b, const unsigned short* __restrict__ wt1b,
    const float* __restrict__ cb1, const float* __restrict__ bnab0,
    float* __restrict__ sb,
    unsigned short* __restrict__ y1b)
{
    __shared__ __align__(16) unsigned short W1B[64*72];
    __shared__ __align__(16) unsigned short STG[64*72];
    __shared__ float sAcc[64], qAcc[64];
    const int tid = threadIdx.x;
    const int r0 = blockIdx.x * 64;
    const int lane = tid & 63, wv = tid >> 6;
    const int mrow = lane & 15, quad = lane >> 4;

    {
        const uint4* s = (const uint4*)wt1b;
        for (int i = tid; i < 512; i += 256) {
            int r = i >> 3, ch = i & 7;
            *(uint4*)(W1B + r*72 + ch*8) = s[i];
        }
    }
    if (tid < 64) { sAcc[tid] = 0.f; qAcc[tid] = 0.f; }

    const int gr = r0 + wv*16 + mrow;
    bf16x8 raw0 = *(const bf16x8*)(y0b + (size_t)gr*64 + quad*8);
    bf16x8 raw1 = *(const bf16x8*)(y0b + (size_t)gr*64 + 32 + quad*8);
    bf16x8 a0, a1;
    {
        const float* A = bnab0 + quad*8;
        const float* S = bnab0 + 64 + quad*8;
#pragma unroll
        for (int j = 0; j < 8; ++j) {
            float f = ubf((unsigned short)raw0[j]);
            a0[j] = (short)bf16u(fmaxf(fmaf(A[j], f, S[j]), 0.f));
        }
        const float* A2 = bnab0 + 32 + quad*8;
        const float* S2 = bnab0 + 96 + quad*8;
#pragma unroll
        for (int j = 0; j < 8; ++j) {
            float f = ubf((unsigned short)raw1[j]);
            a1[j] = (short)bf16u(fmaxf(fmaf(A2[j], f, S2[j]), 0.f));
        }
    }
    __syncthreads();

    f32x4 acc[4];
#pragma unroll
    for (int ct = 0; ct < 4; ++ct) {
        float bv = cb1[ct*16 + mrow];
        acc[ct] = (f32x4){bv, bv, bv, bv};
    }
#pragma unroll
    for (int ct = 0; ct < 4; ++ct) {
        bf16x8 b0 = *(const bf16x8*)(W1B + (ct*16 + mrow)*72 + quad*8);
        bf16x8 b1 = *(const bf16x8*)(W1B + (ct*16 + mrow)*72 + 32 + quad*8);
        acc[ct] = __builtin_amdgcn_mfma_f32_16x16x32_bf16(a0, b0, acc[ct], 0, 0, 0);
        acc[ct] = __builtin_amdgcn_mfma_f32_16x16x32_bf16(a1, b1, acc[ct], 0, 0, 0);
    }
#pragma unroll
    for (int ct = 0; ct < 4; ++ct) {
        f32x4 v = acc[ct];
        float s = (v.x + v.y) + (v.z + v.w);
        float q = (v.x*v.x + v.y*v.y) + (v.z*v.z + v.w*v.w);
        atomicAdd(&sAcc[ct*16 + mrow], s);
        atomicAdd(&qAcc[ct*16 + mrow], q);
    }
    const int rbase = wv*16 + quad*4;
#pragma unroll
    for (int ct = 0; ct < 4; ++ct) {
        int col = ct*16 + mrow;
        f32x4 v = acc[ct];
        STG[(rbase+0)*72 + col] = (unsigned short)bf16u(v.x);
        STG[(rbase+1)*72 + col] = (unsigned short)bf16u(v.y);
        STG[(rbase+2)*72 + col] = (unsigned short)bf16u(v.z);
        STG[(rbase+3)*72 + col] = (unsigned short)bf16u(v.w);
    }
    __syncthreads();
    for (int i = tid; i < 512; i += 256) {
        int r = i >> 3, c8 = i & 7;
        *(uint4*)(y1b + (size_t)(r0 + r)*64 + c8*8) = *(const uint4*)(STG + r*72 + c8*8);
    }
    int bk = blockIdx.x & 63;
    if (tid < 64) {
        atomicAdd(sb + bk*64 + tid, sAcc[tid]);
        atomicAdd(sb + 4096 + bk*64 + tid, qAcc[tid]);
    }
}

// pass2: stream Y1, bn1+relu, L2 MFMA (128 out), stats2 + packed extrema.
__global__ __launch_bounds__(256) void pass2_kernel(
    const unsigned short* __restrict__ y1b, const unsigned short* __restrict__ wt2b,
    const float* __restrict__ cb2, const float* __restrict__ bnab1,
    float* __restrict__ sb,
    unsigned int* __restrict__ packed)
{
    __shared__ __align__(16) unsigned short W2B[128*72];
    __shared__ float sAcc[128], qAcc[128];
    __shared__ float mxs[4*128], mns[4*128];
    const int tid = threadIdx.x;
    const int r0 = blockIdx.x * 64;
    const int lane = tid & 63, wv = tid >> 6;
    const int mrow = lane & 15, quad = lane >> 4;

    {
        const uint4* s = (const uint4*)wt2b;
        for (int i = tid; i < 1024; i += 256) {
            int r = i >> 3, ch = i & 7;
            *(uint4*)(W2B + r*72 + ch*8) = s[i];
        }
    }
    if (tid < 128) { sAcc[tid] = 0.f; qAcc[tid] = 0.f; }

    const int gr = r0 + wv*16 + mrow;
    bf16x8 raw0 = *(const bf16x8*)(y1b + (size_t)gr*64 + quad*8);
    bf16x8 raw1 = *(const bf16x8*)(y1b + (size_t)gr*64 + 32 + quad*8);
    bf16x8 a0, a1;
    {
        const float* A = bnab1 + quad*8;
        const float* S = bnab1 + 64 + quad*8;
#pragma unroll
        for (int j = 0; j < 8; ++j) {
            float f = ubf((unsigned short)raw0[j]);
            a0[j] = (short)bf16u(fmaxf(fmaf(A[j], f, S[j]), 0.f));
        }
        const float* A2 = bnab1 + 32 + quad*8;
        const float* S2 = bnab1 + 96 + quad*8;
#pragma unroll
        for (int j = 0; j < 8; ++j) {
            float f = ubf((unsigned short)raw1[j]);
            a1[j] = (short)bf16u(fmaxf(fmaf(A2[j], f, S2[j]), 0.f));
        }
    }
    __syncthreads();

    f32x4 acc[8];
#pragma unroll
    for (int ct = 0; ct < 8; ++ct) {
        float bv = cb2[ct*16 + mrow];
        acc[ct] = (f32x4){bv, bv, bv, bv};
    }
#pragma unroll
    for (int ct = 0; ct < 8; ++ct) {
        bf16x8 b0 = *(const bf16x8*)(W2B + (ct*16 + mrow)*72 + quad*8);
        bf16x8 b1 = *(const bf16x8*)(W2B + (ct*16 + mrow)*72 + 32 + quad*8);
        acc[ct] = __builtin_amdgcn_mfma_f32_16x16x32_bf16(a0, b0, acc[ct], 0, 0, 0);
        acc[ct] = __builtin_amdgcn_mfma_f32_16x16x32_bf16(a1, b1, acc[ct], 0, 0, 0);
    }
#pragma unroll
    for (int ct = 0; ct < 8; ++ct) {
        f32x4 v = acc[ct];
        float s = (v.x + v.y) + (v.z + v.w);
        float q = (v.x*v.x + v.y*v.y) + (v.z*v.z + v.w*v.w);
        atomicAdd(&sAcc[ct*16 + mrow], s);
        atomicAdd(&qAcc[ct*16 + mrow], q);
    }
#pragma unroll
    for (int ct = 0; ct < 8; ++ct) {
        f32x4 v = acc[ct];
        float mx = fmaxf(fmaxf(v.x, v.y), fmaxf(v.z, v.w));
        float mn = fminf(fminf(v.x, v.y), fminf(v.z, v.w));
        { float o = __shfl_xor(mx, 16); mx = fmaxf(mx, o); }
        { float o = __shfl_xor(mn, 16); mn = fminf(mn, o); }
        { float o = __shfl_xor(mx, 32); mx = fmaxf(mx, o); }
        { float o = __shfl_xor(mn, 32); mn = fminf(mn, o); }
        if (quad == 0) {
            mxs[wv*128 + ct*16 + mrow] = mx;
            mns[wv*128 + ct*16 + mrow] = mn;
        }
    }
    __syncthreads();
    {
        int g = tid >> 7, c = tid & 127;
        float mx = fmaxf(mxs[(2*g)*128 + c], mxs[(2*g+1)*128 + c]);
        float mn = fminf(mns[(2*g)*128 + c], mns[(2*g+1)*128 + c]);
        packed[(size_t)(blockIdx.x*2 + g)*128 + c] = (bf16u(mx) << 16) | bf16u(mn);
    }
    int bk = blockIdx.x & 63;
    if (tid < 128) {
        atomicAdd(sb + bk*128 + tid, sAcc[tid]);
        atomicAdd(sb + 8192 + bk*128 + tid, qAcc[tid]);
    }
}

// ================== FALLBACK PATH (recompute, direct atomics) ==============
template<int DEPTH>
__global__ __launch_bounds__(256) void mlp_pass(
    const float* __restrict__ xyz, const float* __restrict__ points,
    const float* __restrict__ nxw, const int* __restrict__ kidx,
    const unsigned short* __restrict__ wt0b, const unsigned short* __restrict__ wt1b,
    const unsigned short* __restrict__ wt2b,
    const float* __restrict__ cb0, const float* __restrict__ cb1,
    const float* __restrict__ cb2,
    const float* __restrict__ bnab0, const float* __restrict__ bnab1,
    float* __restrict__ statS, float* __restrict__ statQ,
    unsigned int* __restrict__ packed)
{
    __shared__ __align__(16) unsigned short XsB[64*104];
    __shared__ __align__(16) unsigned short W0B[64*104];
    __shared__ __align__(16) unsigned short W1B[(DEPTH>=2) ? 64*72 : 8];
    __shared__ __align__(16) unsigned short W2B[(DEPTH==3) ? 128*72 : 8];
    __shared__ __align__(16) unsigned short Gb [(DEPTH>=2) ? 64*72 : 8];
    __shared__ float sAcc[128], qAcc[128];
    __shared__ float mxs[(DEPTH==3) ? 4*128 : 1];
    __shared__ float mns[(DEPTH==3) ? 4*128 : 1];

    const int tid = threadIdx.x;
    const int r0 = blockIdx.x * 64;
    const int lane = tid & 63, wv = tid >> 6;
    const int mrow = lane & 15, quad = lane >> 4;

    {
        const uint4* s = (const uint4*)wt0b;
        for (int i = tid; i < 768; i += 256) {
            int r = i / 12, ch = i - r*12;
            *(uint4*)(W0B + r*104 + ch*8) = s[i];
        }
    }
    if constexpr (DEPTH >= 2) {
        const uint4* s = (const uint4*)wt1b;
        for (int i = tid; i < 512; i += 256) {
            int r = i >> 3, ch = i & 7;
            *(uint4*)(W1B + r*72 + ch*8) = s[i];
        }
    }
    if constexpr (DEPTH == 3) {
        const uint4* s = (const uint4*)wt2b;
        for (int i = tid; i < 1024; i += 256) {
            int r = i >> 3, ch = i & 7;
            *(uint4*)(W2B + r*72 + ch*8) = s[i];
        }
    }
    if (tid < 128) { sAcc[tid] = 0.f; qAcc[tid] = 0.f; }

    for (int i = tid; i < 64*96; i += 256) {
        int r = i / 96, c = i - r*96;
        int gr = r0 + r;
        int q = gr >> 5;
        int n = kidx[gr];
        int bb = q >> 10;
        float v = 0.f;
        if (c < 64)      v = points[((size_t)(bb*N_ + n))*64 + c];
        else if (c < 67) v = xyz[((size_t)(bb*N_ + n))*3 + (c-64)] - nxw[q*3 + (c-64)];
        XsB[r*104 + c] = (unsigned short)bf16u(v);
    }
    __syncthreads();

    const int arow = wv*16 + mrow;
    f32x4 acc0[4];
#pragma unroll
    for (int ct = 0; ct < 4; ++ct) {
        float bv = cb0[ct*16 + mrow];
        acc0[ct] = (f32x4){bv, bv, bv, bv};
    }
#pragma unroll
    for (int kk = 0; kk < 96; kk += 32) {
        bf16x8 a = *(const bf16x8*)(XsB + arow*104 + kk + quad*8);
#pragma unroll
        for (int ct = 0; ct < 4; ++ct) {
            bf16x8 b = *(const bf16x8*)(W0B + (ct*16 + mrow)*104 + kk + quad*8);
            acc0[ct] = __builtin_amdgcn_mfma_f32_16x16x32_bf16(a, b, acc0[ct], 0, 0, 0);
        }
    }

    if constexpr (DEPTH == 1) {
#pragma unroll
        for (int ct = 0; ct < 4; ++ct) {
            f32x4 v = acc0[ct];
            float s = (v.x + v.y) + (v.z + v.w);
            float q = (v.x*v.x + v.y*v.y) + (v.z*v.z + v.w*v.w);
            atomicAdd(&sAcc[ct*16 + mrow], s);
            atomicAdd(&qAcc[ct*16 + mrow], q);
        }
        __syncthreads();
        if (tid < 64) { atomicAdd(statS + tid, sAcc[tid]); atomicAdd(statQ + tid, qAcc[tid]); }
        return;
    } else {
        const int rbase = wv*16 + quad*4;
#pragma unroll
        for (int ct = 0; ct < 4; ++ct) {
            int col = ct*16 + mrow;
            float a = bnab0[col], sh = bnab0[64 + col];
            f32x4 v = acc0[ct];
            Gb[(rbase+0)*72 + col] = (unsigned short)bf16u(fmaxf(fmaf(a, v.x, sh), 0.f));
            Gb[(rbase+1)*72 + col] = (unsigned short)bf16u(fmaxf(fmaf(a, v.y, sh), 0.f));
            Gb[(rbase+2)*72 + col] = (unsigned short)bf16u(fmaxf(fmaf(a, v.z, sh), 0.f));
            Gb[(rbase+3)*72 + col] = (unsigned short)bf16u(fmaxf(fmaf(a, v.w, sh), 0.f));
        }
        f32x4 acc1[4];
#pragma unroll
        for (int ct = 0; ct < 4; ++ct) {
            float bv = cb1[ct*16 + mrow];
            acc1[ct] = (f32x4){bv, bv, bv, bv};
        }
#pragma unroll
        for (int kk = 0; kk < 64; kk += 32) {
            bf16x8 a = *(const bf16x8*)(Gb + arow*72 + kk + quad*8);
#pragma unroll
            for (int ct = 0; ct < 4; ++ct) {
                bf16x8 b = *(const bf16x8*)(W1B + (ct*16 + mrow)*72 + kk + quad*8);
                acc1[ct] = __builtin_amdgcn_mfma_f32_16x16x32_bf16(a, b, acc1[ct], 0, 0, 0);
            }
        }
        if constexpr (DEPTH == 2) {
#pragma unroll
            for (int ct = 0; ct < 4; ++ct) {
                f32x4 v = acc1[ct];
                float s = (v.x + v.y) + (v.z + v.w);
                float q = (v.x*v.x + v.y*v.y) + (v.z*v.z + v.w*v.w);
                atomicAdd(&sAcc[ct*16 + mrow], s);
                atomicAdd(&qAcc[ct*16 + mrow], q);
            }
            __syncthreads();
            if (tid < 64) { atomicAdd(statS + tid, sAcc[tid]); atomicAdd(statQ + tid, qAcc[tid]); }
            return;
        } else {
#pragma unroll
            for (int ct = 0; ct < 4; ++ct) {
                int col = ct*16 + mrow;
                float a = bnab1[col], sh = bnab1[64 + col];
                f32x4 v = acc1[ct];
                Gb[(rbase+0)*72 + col] = (unsigned short)bf16u(fmaxf(fmaf(a, v.x, sh), 0.f));
                Gb[(rbase+1)*72 + col] = (unsigned short)bf16u(fmaxf(fmaf(a, v.y, sh), 0.f));
                Gb[(rbase+2)*72 + col] = (unsigned short)bf16u(fmaxf(fmaf(a, v.z, sh), 0.f));
                Gb[(rbase+3)*72 + col] = (unsigned short)bf16u(fmaxf(fmaf(a, v.w, sh), 0.f));
            }
            f32x4 acc2[8];
#pragma unroll
            for (int ct = 0; ct < 8; ++ct) {
                float bv = cb2[ct*16 + mrow];
                acc2[ct] = (f32x4){bv, bv, bv, bv};
            }
#pragma unroll
            for (int kk = 0; kk < 64; kk += 32) {
                bf16x8 a = *(const bf16x8*)(Gb + arow*72 + kk + quad*8);
#pragma unroll
                for (int ct = 0; ct < 8; ++ct) {
                    bf16x8 b = *(const bf16x8*)(W2B + (ct*16 + mrow)*72 + kk + quad*8);
                    acc2[ct] = __builtin_amdgcn_mfma_f32_16x16x32_bf16(a, b, acc2[ct], 0, 0, 0);
                }
            }
#pragma unroll
            for (int ct = 0; ct < 8; ++ct) {
                f32x4 v = acc2[ct];
                float s = (v.x + v.y) + (v.z + v.w);
                float q = (v.x*v.x + v.y*v.y) + (v.z*v.z + v.w*v.w);
                atomicAdd(&sAcc[ct*16 + mrow], s);
                atomicAdd(&qAcc[ct*16 + mrow], q);
            }
#pragma unroll
            for (int ct = 0; ct < 8; ++ct) {
                f32x4 v = acc2[ct];
                float mx = fmaxf(fmaxf(v.x, v.y), fmaxf(v.z, v.w));
                float mn = fminf(fminf(v.x, v.y), fminf(v.z, v.w));
                { float o = __shfl_xor(mx, 16); mx = fmaxf(mx, o); }
                { float o = __shfl_xor(mn, 16); mn = fminf(mn, o); }
                { float o = __shfl_xor(mx, 32); mx = fmaxf(mx, o); }
                { float o = __shfl_xor(mn, 32); mn = fminf(mn, o); }
                if (quad == 0) {
                    mxs[wv*128 + ct*16 + mrow] = mx;
                    mns[wv*128 + ct*16 + mrow] = mn;
                }
            }
            __syncthreads();
            {
                int g = tid >> 7, c = tid & 127;
                float mx = fmaxf(mxs[(2*g)*128 + c], mxs[(2*g+1)*128 + c]);
                float mn = fminf(mns[(2*g)*128 + c], mns[(2*g+1)*128 + c]);
                packed[(size_t)(blockIdx.x*2 + g)*128 + c] = (bf16u(mx) << 16) | bf16u(mn);
            }
            if (tid < 128) { atomicAdd(statS + tid, sAcc[tid]); atomicAdd(statQ + tid, qAcc[tid]); }
        }
    }
}

// ---------------- BN finalize: direct (fallback) ----------------
template<int COUT>
__global__ void bn_finalize(const float* __restrict__ stat_s, const float* __restrict__ stat_q,
                            const float* __restrict__ gamma, const float* __restrict__ beta,
                            float* __restrict__ bnab) {
    int c = threadIdx.x;
    if (c < COUT) {
        const float inv_n = 1.f / (float)RTOT;
        float mu  = stat_s[c] * inv_n;
        float var = stat_q[c] * inv_n - mu*mu;
        float inv = 1.f / sqrtf(var + EPSF);
        float a = gamma[c] * inv;
        bnab[c] = a;
        bnab[COUT + c] = beta[c] - mu * a;
    }
}

// ---------------- BN finalize: bucketed (fast path) ----------------
template<int COUT>
__global__ void bn_finalize_bk(const float* __restrict__ sb,
                               const float* __restrict__ gamma, const float* __restrict__ beta,
                               float* __restrict__ bnab) {
    int c = threadIdx.x;
    if (c < COUT) {
        float s = 0.f, q = 0.f;
        for (int k = 0; k < 64; ++k) {
            s += sb[k*COUT + c];
            q += sb[64*COUT + k*COUT + c];
        }
        const float inv_n = 1.f / (float)RTOT;
        float mu  = s * inv_n;
        float var = q * inv_n - mu*mu;
        float inv = 1.f / sqrtf(var + EPSF);
        float a = gamma[c] * inv;
        bnab[c] = a;
        bnab[COUT + c] = beta[c] - mu * a;
    }
}

// ---------------- final: BN2+ReLU on pooled extrema ----------------
__global__ __launch_bounds__(256) void final_out(const unsigned int* __restrict__ packed,
                                                 const float* __restrict__ bnab2,
                                                 float* __restrict__ out_np) {
    int idx = blockIdx.x*256 + threadIdx.x;
    int c = idx & 127;
    float a = bnab2[c], sh = bnab2[128 + c];
    unsigned p = packed[idx];
    float mx = __uint_as_float(p & 0xFFFF0000u);
    float mn = __uint_as_float(p << 16);
    float x = (a >= 0.f) ? mx : mn;
    out_np[idx] = fmaxf(fmaf(a, x, sh), 0.f);
}

extern "C" void kernel_launch(void* const* d_in, const int* in_sizes, int n_in,
                              void* d_out, int out_size, void* d_ws, size_t ws_size,
                              hipStream_t stream) {
    const float* xyz    = (const float*)d_in[0];
    const float* points = (const float*)d_in[1];
    const float* W0 = (const float*)d_in[2];
    const float* b0 = (const float*)d_in[3];
    const float* g0 = (const float*)d_in[4];
    const float* be0= (const float*)d_in[5];
    const float* W1 = (const float*)d_in[6];
    const float* b1 = (const float*)d_in[7];
    const float* g1 = (const float*)d_in[8];
    const float* be1= (const float*)d_in[9];
    const float* W2 = (const float*)d_in[10];
    const float* b2 = (const float*)d_in[11];
    const float* g2 = (const float*)d_in[12];
    const float* be2= (const float*)d_in[13];

    float* ws  = (float*)d_ws;
    float* out = (float*)d_out;
    float* out_newxyz = out;                        // 49152
    float* out_np     = out + 49152;                // 2097152
    float* out_fpsidx = out + 49152 + 2097152;      // 16384

    unsigned short* wt0b = (unsigned short*)(ws + WT0B_OFF);
    unsigned short* wt1b = (unsigned short*)(ws + WT1B_OFF);
    unsigned short* wt2b = (unsigned short*)(ws + WT2B_OFF);
    float* s0 = ws + ST_OFF;        float* q0 = s0 + 64;
    float* s1 = q0 + 64;            float* q1 = s1 + 64;
    float* s2 = q1 + 64;            float* q2 = s2 + 128;
    float* bnab0 = ws + BN_OFF;     float* bnab1 = bnab0 + 128;  float* bnab2 = bnab1 + 128;
    float* nxw   = ws + NXW_OFF;
    int*   kidx  = (int*)(ws + KIDX_OFF);
    unsigned int* packed = (unsigned int*)(ws + PK_OFF);
    unsigned short* y0b = (unsigned short*)(ws + Y0B_OFF);
    unsigned short* y1b = (unsigned short*)(ws + Y1B_OFF);
    float* sb0 = ws + SB0_OFF;
    float* sb1 = ws + SB1_OFF;
    float* sb2 = ws + SB2_OFF;

    int fast = (ws_size >= WS_FAST_BYTES) ? 1 : 0;

    prep_kernel<<<17, 256, 0, stream>>>(W0, W1, W2, ws, fast);
    fps_kernel<<<B_, 256, 0, stream>>>(xyz, out_newxyz, out_fpsidx, nxw);
    knn_kernel<<<(B_*M_)/4, 256, 0, stream>>>(xyz, nxw, kidx);

    if (fast) {
        pass0_kernel<<<RTOT/64, 256, 0, stream>>>(xyz, points, nxw, kidx, wt0b, b0, sb0, y0b);
        bn_finalize_bk<64><<<1, 64, 0, stream>>>(sb0, g0, be0, bnab0);
        pass1_kernel<<<RTOT/64, 256, 0, stream>>>(y0b, wt1b, b1, bnab0, sb1, y1b);
        bn_finalize_bk<64><<<1, 64, 0, stream>>>(sb1, g1, be1, bnab1);
        pass2_kernel<<<RTOT/64, 256, 0, stream>>>(y1b, wt2b, b2, bnab1, sb2, packed);
        bn_finalize_bk<128><<<1, 128, 0, stream>>>(sb2, g2, be2, bnab2);
    } else {
        mlp_pass<1><<<RTOT/64, 256, 0, stream>>>(xyz, points, nxw, kidx, wt0b, wt1b, wt2b,
            b0, b1, b2, nullptr, nullptr, s0, q0, nullptr);
        bn_finalize<64><<<1, 64, 0, stream>>>(s0, q0, g0, be0, bnab0);
        mlp_pass<2><<<RTOT/64, 256, 0, stream>>>(xyz, points, nxw, kidx, wt0b, wt1b, wt2b,
            b0, b1, b2, bnab0, nullptr, s1, q1, nullptr);
        bn_finalize<64><<<1, 64, 0, stream>>>(s1, q1, g1, be1, bnab1);
        mlp_pass<3><<<RTOT/64, 256, 0, stream>>>(xyz, points, nxw, kidx, wt0b, wt1b, wt2b,
            b0, b1, b2, bnab0, bnab1, s2, q2, packed);
        bn_finalize<128><<<1, 128, 0, stream>>>(s2, q2, g2, be2, bnab2);
    }

    final_out<<<(B_*M_*128)/256, 256, 0, stream>>>(packed, bnab2, out_np);
}